// Round 1
// baseline (486.890 us; speedup 1.0000x reference)
//
#include <hip/hip_runtime.h>
#include <cstdint>
#include <cstddef>

// ---------------- problem constants ----------------
#define NTOK 8192            // B*T = 4*2048
#define WD   4096            // n*C
#define CD   1024            // C (per-stream channels)
#define EPS_RMS 1.1920929e-07f
#define TAU_INV 10.0f        // 1/0.1

using half8  = __attribute__((ext_vector_type(8))) _Float16;
using half4v = __attribute__((ext_vector_type(4))) _Float16;
using f32x4  = __attribute__((ext_vector_type(4))) float;

// ================= Kernel A: W_branch fp32 [k][c] -> WT f16 [c][k] =================
__global__ __launch_bounds__(256) void k_wt(const float* __restrict__ W,
                                            _Float16* __restrict__ WT) {
  __shared__ float tile[64][65];        // +1 pad: conflict-free column reads
  const int t  = threadIdx.x;
  const int c0 = (blockIdx.x & 15) * 64;
  const int k0 = (blockIdx.x >> 4) * 64;
  const int a = t & 63, b = t >> 6;     // a: fast index, b: 0..3
#pragma unroll
  for (int i = 0; i < 16; ++i) {
    int k = b + i * 4;
    tile[k][a] = W[(size_t)(k0 + k) * CD + (c0 + a)];   // coalesced in c
  }
  __syncthreads();
#pragma unroll
  for (int i = 0; i < 16; ++i) {
    int c = b + i * 4;
    WT[(size_t)(c0 + c) * CD + (k0 + a)] = (_Float16)tile[a][c];  // coalesced in k
  }
}

// ================= Kernel B: per-token stats =================
// block = 256 thr = 4 waves; each 16-lane quarter owns one token -> 16 tokens/block.
// Produces: res logits (16/tok), H_post probs (4/tok), x_pre f16 (1024/tok).
__global__ __launch_bounds__(256, 2) void k_stats(
    const float* __restrict__ x,
    const float* __restrict__ Wres, const float* __restrict__ Wpre,
    const float* __restrict__ Wpost, const float* __restrict__ baseRes,
    const float* __restrict__ basePre, const float* __restrict__ basePost,
    float* __restrict__ Zout, float* __restrict__ HpostOut,
    _Float16* __restrict__ xpre)
{
  const int tid  = threadIdx.x;
  const int lane = tid & 63;
  const int wid  = tid >> 6;
  const int l16  = lane & 15;
  const int tok  = blockIdx.x * 16 + wid * 4 + (lane >> 4);
  const float* xr = x + (size_t)tok * WD;

  float accR[16], accP[4], accQ[4], accS = 0.0f;
#pragma unroll
  for (int j = 0; j < 16; ++j) accR[j] = 0.0f;
#pragma unroll
  for (int j = 0; j < 4; ++j) { accP[j] = 0.0f; accQ[j] = 0.0f; }

  // ---- phase 1: 25 reductions over 4096 channels (64 floats/iter/quarter) ----
#pragma unroll 2
  for (int it = 0; it < 64; ++it) {
    const int c4 = it * 64 + l16 * 4;
    const float4 xv = *(const float4*)(xr + c4);
    accS += xv.x * xv.x + xv.y * xv.y + xv.z * xv.z + xv.w * xv.w;
#pragma unroll
    for (int j = 0; j < 16; ++j) {
      const float4 w = *(const float4*)(Wres + (size_t)j * WD + c4);
      accR[j] += w.x * xv.x + w.y * xv.y + w.z * xv.z + w.w * xv.w;
    }
#pragma unroll
    for (int j = 0; j < 4; ++j) {
      const float4 w = *(const float4*)(Wpre + (size_t)j * WD + c4);
      accP[j] += w.x * xv.x + w.y * xv.y + w.z * xv.z + w.w * xv.w;
    }
#pragma unroll
    for (int j = 0; j < 4; ++j) {
      const float4 w = *(const float4*)(Wpost + (size_t)j * WD + c4);
      accQ[j] += w.x * xv.x + w.y * xv.y + w.z * xv.z + w.w * xv.w;
    }
  }

  // ---- butterfly reduce within the 16-lane quarter (xor 1,2,4,8) ----
#define QR(v) { v += __shfl_xor(v, 1); v += __shfl_xor(v, 2); \
                v += __shfl_xor(v, 4); v += __shfl_xor(v, 8); }
  QR(accS)
#pragma unroll
  for (int j = 0; j < 16; ++j) QR(accR[j])
#pragma unroll
  for (int j = 0; j < 4; ++j) QR(accP[j])
#pragma unroll
  for (int j = 0; j < 4; ++j) QR(accQ[j])
#undef QR

  const float inv = rsqrtf(accS * (1.0f / (float)WD) + EPS_RMS);

  // ---- res logits -> Zout (lane l16 stores element l16; static-index select) ----
  float zval = 0.0f;
#pragma unroll
  for (int e = 0; e < 16; ++e) {
    const float v = fmaf(accR[e], inv, baseRes[e]);
    if (l16 == e) zval = v;
  }
  Zout[(size_t)tok * 16 + l16] = zval;

  // ---- H_pre softmax (kept in registers, all lanes) ----
  float p[4];
#pragma unroll
  for (int j = 0; j < 4; ++j) p[j] = fmaf(accP[j], inv, basePre[j]);
  {
    const float m = fmaxf(fmaxf(p[0], p[1]), fmaxf(p[2], p[3]));
    float s = 0.0f;
#pragma unroll
    for (int j = 0; j < 4; ++j) { p[j] = __expf(p[j] - m); s += p[j]; }
    const float rs = 1.0f / s;
#pragma unroll
    for (int j = 0; j < 4; ++j) p[j] *= rs;
  }

  // ---- H_post softmax -> store ----
  {
    float q[4];
#pragma unroll
    for (int j = 0; j < 4; ++j) q[j] = fmaf(accQ[j], inv, basePost[j]);
    const float m = fmaxf(fmaxf(q[0], q[1]), fmaxf(q[2], q[3]));
    float s = 0.0f;
#pragma unroll
    for (int j = 0; j < 4; ++j) { q[j] = __expf(q[j] - m); s += q[j]; }
    const float rs = 1.0f / s;
    float hv = 0.0f;
#pragma unroll
    for (int e = 0; e < 4; ++e) { if (l16 == e) hv = q[e] * rs; }
    if (l16 < 4) HpostOut[(size_t)tok * 4 + l16] = hv;
  }

  // ---- phase 2: x_pre = sum_n Hpre[n] * x[n*C + c]  (f16 out) ----
  _Float16* xp = xpre + (size_t)tok * CD;
#pragma unroll 2
  for (int it = 0; it < 16; ++it) {
    const int c4 = it * 64 + l16 * 4;
    const float4 a0 = *(const float4*)(xr + c4);
    const float4 a1 = *(const float4*)(xr + CD + c4);
    const float4 a2 = *(const float4*)(xr + 2 * CD + c4);
    const float4 a3 = *(const float4*)(xr + 3 * CD + c4);
    half4v h;
    h[0] = (_Float16)(p[0] * a0.x + p[1] * a1.x + p[2] * a2.x + p[3] * a3.x);
    h[1] = (_Float16)(p[0] * a0.y + p[1] * a1.y + p[2] * a2.y + p[3] * a3.y);
    h[2] = (_Float16)(p[0] * a0.z + p[1] * a1.z + p[2] * a2.z + p[3] * a3.z);
    h[3] = (_Float16)(p[0] * a0.w + p[1] * a1.w + p[2] * a2.w + p[3] * a3.w);
    *(half4v*)(xp + c4) = h;
  }
}

// ================= Kernel C: log-domain Sinkhorn (50 iters) + gate =================
// 16 lanes per token: lane = i*4+j. Row reduce: xor 1,2. Col reduce: xor 4,8.
__global__ __launch_bounds__(256) void k_sinkhorn(const float* __restrict__ Zin,
                                                  const float* __restrict__ gate,
                                                  float* __restrict__ HresF) {
  const int tid = threadIdx.x;
  const int l16 = tid & 15;
  const int tok = blockIdx.x * 16 + (tid >> 4);
  const float Z = Zin[(size_t)tok * 16 + l16] * TAU_INV;
  const int i = l16 >> 2, j = l16 & 3;
  float u = 0.0f, v = 0.0f;
  for (int itr = 0; itr < 50; ++itr) {
    // u = -logsumexp_j(Z + v)
    float a = Z + v;
    float m = fmaxf(a, __shfl_xor(a, 1)); m = fmaxf(m, __shfl_xor(m, 2));
    float s = __expf(a - m);
    s += __shfl_xor(s, 1); s += __shfl_xor(s, 2);
    u = -(m + __logf(s));
    // v = -logsumexp_i(Z + u)
    float b = Z + u;
    float m2 = fmaxf(b, __shfl_xor(b, 4)); m2 = fmaxf(m2, __shfl_xor(m2, 8));
    float s2 = __expf(b - m2);
    s2 += __shfl_xor(s2, 4); s2 += __shfl_xor(s2, 8);
    v = -(m2 + __logf(s2));
  }
  const float H = __expf(Z + u + v);
  const float g = 1.0f / (1.0f + __expf(-gate[0]));
  HresF[(size_t)tok * 16 + l16] = g * H + ((i == j) ? (1.0f - g) : 0.0f);
}

// ================= Kernel D: y = x_pre @ W_branch (f16 MFMA) + fused epilogue =====
// 128x128 tile, BK=64, 4 waves each computing a 64x64 quadrant via 4x4 16x16x32 MFMAs.
#define LDK 72   // padded K-stride (f16 elems): 144B rows -> 2-way banks (free)
__global__ __launch_bounds__(256, 2) void k_gemm_epi(
    const _Float16* __restrict__ xpre, const _Float16* __restrict__ WT,
    const float* __restrict__ x, const float* __restrict__ HresF,
    const float* __restrict__ Hpost, float* __restrict__ out)
{
  __shared__ _Float16 As[128 * LDK];
  __shared__ _Float16 Bs[128 * LDK];
  const int tid  = threadIdx.x;
  const int nb   = blockIdx.x & 7;     // consecutive blocks share the A tile (L2/L3)
  const int mb   = blockIdx.x >> 3;
  const int tok0 = mb * 128;
  const int cb   = nb * 128;
  const int lane = tid & 63, wid = tid >> 6;
  const int wr = (wid >> 1) * 64, wc = (wid & 1) * 64;   // wave quadrant
  const int fr = lane & 15, kg = lane >> 4;

  f32x4 acc[4][4];
#pragma unroll
  for (int m = 0; m < 4; ++m)
#pragma unroll
    for (int n = 0; n < 4; ++n) { f32x4 z = {0.f, 0.f, 0.f, 0.f}; acc[m][n] = z; }

  for (int kt = 0; kt < 16; ++kt) {
    // ---- stage A (x_pre rows) and B (WT rows = W^T) tiles, 16B chunks ----
#pragma unroll
    for (int i = 0; i < 4; ++i) {
      const int chunk = tid + i * 256;          // 0..1023
      const int r = chunk >> 3;                 // 0..127
      const int ko = (chunk & 7) * 8;           // 0..56
      *(half8*)&As[r * LDK + ko] =
          *(const half8*)&xpre[(size_t)(tok0 + r) * CD + kt * 64 + ko];
      *(half8*)&Bs[r * LDK + ko] =
          *(const half8*)&WT[(size_t)(cb + r) * CD + kt * 64 + ko];
    }
    __syncthreads();
#pragma unroll
    for (int kk = 0; kk < 2; ++kk) {
      half8 a[4], b[4];
#pragma unroll
      for (int m = 0; m < 4; ++m)
        a[m] = *(const half8*)&As[(wr + m * 16 + fr) * LDK + kk * 32 + kg * 8];
#pragma unroll
      for (int n = 0; n < 4; ++n)
        b[n] = *(const half8*)&Bs[(wc + n * 16 + fr) * LDK + kk * 32 + kg * 8];
#pragma unroll
      for (int m = 0; m < 4; ++m)
#pragma unroll
        for (int n = 0; n < 4; ++n)
          acc[m][n] = __builtin_amdgcn_mfma_f32_16x16x32_f16(a[m], b[n], acc[m][n], 0, 0, 0);
    }
    __syncthreads();
  }

  // ---- epilogue: out[i*C+c] = sum_j Hres[i][j]*x[j*C+c] + Hpost[i]*y[c] ----
  float* Hs = (float*)As;   // reuse LDS: 128 tokens x 20 floats = 10 KB
  for (int idx = tid; idx < 128 * 20; idx += 256) {
    const int tl = idx / 20, e = idx % 20;
    Hs[idx] = (e < 16) ? HresF[(size_t)(tok0 + tl) * 16 + e]
                       : Hpost[(size_t)(tok0 + tl) * 4 + (e - 16)];
  }
  __syncthreads();

#pragma unroll
  for (int m = 0; m < 4; ++m) {
#pragma unroll
    for (int reg = 0; reg < 4; ++reg) {
      const int tl = wr + m * 16 + (lane >> 4) * 4 + reg;  // verified C/D row map
      const size_t trow = (size_t)(tok0 + tl) * WD;
      float H[20];
#pragma unroll
      for (int e = 0; e < 20; ++e) H[e] = Hs[tl * 20 + e];
#pragma unroll
      for (int n = 0; n < 4; ++n) {
        const int c = cb + wc + n * 16 + (lane & 15);      // verified C/D col map
        const float yv = acc[m][n][reg];
        const float x0 = x[trow + c];
        const float x1 = x[trow + CD + c];
        const float x2 = x[trow + 2 * CD + c];
        const float x3 = x[trow + 3 * CD + c];
#pragma unroll
        for (int i = 0; i < 4; ++i) {
          out[trow + i * CD + c] =
              H[i * 4 + 0] * x0 + H[i * 4 + 1] * x1 + H[i * 4 + 2] * x2 +
              H[i * 4 + 3] * x3 + H[16 + i] * yv;
        }
      }
    }
  }
}

// ================= launcher =================
extern "C" void kernel_launch(void* const* d_in, const int* in_sizes, int n_in,
                              void* d_out, int out_size, void* d_ws, size_t ws_size,
                              hipStream_t stream) {
  const float* x        = (const float*)d_in[0];
  const float* Wres     = (const float*)d_in[1];
  const float* Wpre     = (const float*)d_in[2];
  const float* Wpost    = (const float*)d_in[3];
  const float* baseRes  = (const float*)d_in[4];
  const float* basePre  = (const float*)d_in[5];
  const float* basePost = (const float*)d_in[6];
  const float* gate     = (const float*)d_in[7];
  const float* Wb       = (const float*)d_in[8];
  float* out = (float*)d_out;

  char* ws = (char*)d_ws;
  _Float16* xpre  = (_Float16*)(ws);                       // 8192*1024*2  = 16,777,216 B
  _Float16* WT    = (_Float16*)(ws + 16777216);            // 1024*1024*2  =  2,097,152 B
  float*    Z     = (float*)(ws + 18874368);               // 8192*16*4    =    524,288 B
  float*    HresF = (float*)(ws + 19398656);               // 8192*16*4    =    524,288 B
  float*    Hpst  = (float*)(ws + 19922944);               // 8192*4*4     =    131,072 B

  k_wt<<<256, 256, 0, stream>>>(Wb, WT);
  k_stats<<<512, 256, 0, stream>>>(x, Wres, Wpre, Wpost, baseRes, basePre,
                                   basePost, Z, Hpst, xpre);
  k_sinkhorn<<<512, 256, 0, stream>>>(Z, gate, HresF);
  k_gemm_epi<<<512, 256, 0, stream>>>(xpre, WT, x, HresF, Hpst, out);
}

// Round 2
// 160.934 us; speedup vs baseline: 3.0254x; 3.0254x over previous
//
#include <hip/hip_runtime.h>
#include <cstdint>
#include <cstddef>

// ---------------- problem constants ----------------
#define NTOK 8192            // B*T = 4*2048
#define WD   4096            // n*C
#define CD   1024            // C (per-stream channels)
#define EPS_RMS 1.1920929e-07f
#define TAU_INV 10.0f        // 1/0.1

using half8  = __attribute__((ext_vector_type(8))) _Float16;
using half4v = __attribute__((ext_vector_type(4))) _Float16;
using f32x4  = __attribute__((ext_vector_type(4))) float;

// ================= Kernel A: W_branch fp32 [k][c] -> WT f16 [c][k] =================
__global__ __launch_bounds__(256) void k_wt(const float* __restrict__ W,
                                            _Float16* __restrict__ WT) {
  __shared__ float tile[64][65];        // +1 pad: conflict-free column reads
  const int t  = threadIdx.x;
  const int c0 = (blockIdx.x & 15) * 64;
  const int k0 = (blockIdx.x >> 4) * 64;
  const int a = t & 63, b = t >> 6;     // a: fast index, b: 0..3
#pragma unroll
  for (int i = 0; i < 16; ++i) {
    int k = b + i * 4;
    tile[k][a] = W[(size_t)(k0 + k) * CD + (c0 + a)];   // coalesced in c
  }
  __syncthreads();
#pragma unroll
  for (int i = 0; i < 16; ++i) {
    int c = b + i * 4;
    WT[(size_t)(c0 + c) * CD + (k0 + a)] = (_Float16)tile[a][c];  // coalesced in k
  }
}

// ================= Kernel A2: concat projection weights -> Wcat f16 [32][4096] ======
// rows 0-15: W_res, 16-19: W_pre, 20-23: W_post, 24-31: zero padding.
__global__ __launch_bounds__(256) void k_wcat(const float* __restrict__ Wres,
                                              const float* __restrict__ Wpre,
                                              const float* __restrict__ Wpost,
                                              _Float16* __restrict__ Wcat) {
  const int id  = blockIdx.x * 256 + threadIdx.x;   // 0..32767 float4 chunks
  const int row = id >> 10;                         // 1024 float4 per 4096-row
  const int kq  = id & 1023;
  float4 v = make_float4(0.f, 0.f, 0.f, 0.f);
  if (row < 16)      v = *(const float4*)(Wres + (size_t)row * WD + kq * 4);
  else if (row < 20) v = *(const float4*)(Wpre + (size_t)(row - 16) * WD + kq * 4);
  else if (row < 24) v = *(const float4*)(Wpost + (size_t)(row - 20) * WD + kq * 4);
  half4v h;
  h[0] = (_Float16)v.x; h[1] = (_Float16)v.y; h[2] = (_Float16)v.z; h[3] = (_Float16)v.w;
  *(half4v*)(Wcat + (size_t)row * WD + kq * 4) = h;
}

// ================= Kernel B: MFMA stats =================
// block = 128 thr (2 waves), 16 tokens/block, N=32 (24 logits + 8 pad), K=4096.
// Wave w handles n-group w (cols w*16..w*16+15). Fused: sumsq (exact f32),
// Z res-logits, pre/post softmax, and phase-2 x_pre (f16) from Hpre.
#define LDA 72   // padded K-stride in f16 elems
__global__ __launch_bounds__(128) void k_stats2(
    const float* __restrict__ x, const _Float16* __restrict__ Wcat,
    const float* __restrict__ baseRes, const float* __restrict__ basePre,
    const float* __restrict__ basePost,
    float* __restrict__ Zout, float* __restrict__ HpostOut,
    _Float16* __restrict__ xpre)
{
  __shared__ _Float16 As[16 * LDA];
  __shared__ _Float16 Bs[32 * LDA];
  __shared__ float L[16][32];
  __shared__ float sums[16];
  __shared__ float HpreS[16][4];

  const int t    = threadIdx.x;          // 0..127
  const int lane = t & 63;
  const int w    = t >> 6;               // wave id = n-group
  const int tok0 = blockIdx.x * 16;
  const int fr   = lane & 15, kg = lane >> 4;

  // staging ownership (fixed across K-steps)
  const int ar0 = t >> 4;                // A rows ar0, ar0+8; 16 f32 cols each
  const int ak  = (t & 15) * 4;
  const int br0 = t >> 3;                // B rows br0, br0+16
  const int bk  = (t & 7) * 8;

  f32x4 acc = {0.f, 0.f, 0.f, 0.f};
  float ss0 = 0.f, ss1 = 0.f;

  // ---- preload step 0 ----
  float4 a0 = *(const float4*)(x + (size_t)(tok0 + ar0) * WD + ak);
  float4 a1 = *(const float4*)(x + (size_t)(tok0 + ar0 + 8) * WD + ak);
  half8 b0 = *(const half8*)(Wcat + (size_t)br0 * WD + bk);
  half8 b1 = *(const half8*)(Wcat + (size_t)(br0 + 16) * WD + bk);

  for (int kt = 0; kt < 64; ++kt) {
    // ---- commit staged regs to LDS (+ exact-f32 sumsq) ----
    ss0 += a0.x * a0.x + a0.y * a0.y + a0.z * a0.z + a0.w * a0.w;
    ss1 += a1.x * a1.x + a1.y * a1.y + a1.z * a1.z + a1.w * a1.w;
    half4v h0, h1;
    h0[0] = (_Float16)a0.x; h0[1] = (_Float16)a0.y; h0[2] = (_Float16)a0.z; h0[3] = (_Float16)a0.w;
    h1[0] = (_Float16)a1.x; h1[1] = (_Float16)a1.y; h1[2] = (_Float16)a1.z; h1[3] = (_Float16)a1.w;
    *(half4v*)&As[ar0 * LDA + ak] = h0;
    *(half4v*)&As[(ar0 + 8) * LDA + ak] = h1;
    *(half8*)&Bs[br0 * LDA + bk] = b0;
    *(half8*)&Bs[(br0 + 16) * LDA + bk] = b1;
    __syncthreads();

    // ---- prefetch step kt+1 into regs (overlaps MFMA below) ----
    if (kt < 63) {
      const int ko = (kt + 1) * 64;
      a0 = *(const float4*)(x + (size_t)(tok0 + ar0) * WD + ko + ak);
      a1 = *(const float4*)(x + (size_t)(tok0 + ar0 + 8) * WD + ko + ak);
      b0 = *(const half8*)(Wcat + (size_t)br0 * WD + ko + bk);
      b1 = *(const half8*)(Wcat + (size_t)(br0 + 16) * WD + ko + bk);
    }

    // ---- fragments + MFMA (same validated pattern as k_gemm_epi) ----
    half8 af0 = *(const half8*)&As[fr * LDA + kg * 8];
    half8 af1 = *(const half8*)&As[fr * LDA + 32 + kg * 8];
    half8 bf0 = *(const half8*)&Bs[(w * 16 + fr) * LDA + kg * 8];
    half8 bf1 = *(const half8*)&Bs[(w * 16 + fr) * LDA + 32 + kg * 8];
    acc = __builtin_amdgcn_mfma_f32_16x16x32_f16(af0, bf0, acc, 0, 0, 0);
    acc = __builtin_amdgcn_mfma_f32_16x16x32_f16(af1, bf1, acc, 0, 0, 0);
    __syncthreads();
  }

  // ---- sumsq: butterfly within 16-lane quarter (threads sharing t>>4) ----
#define QR(v) { v += __shfl_xor(v, 1); v += __shfl_xor(v, 2); \
                v += __shfl_xor(v, 4); v += __shfl_xor(v, 8); }
  QR(ss0) QR(ss1)
#undef QR
  if ((t & 15) == 0) { sums[ar0] = ss0; sums[ar0 + 8] = ss1; }

  // ---- scatter logits to LDS (C/D map: row=kg*4+reg, col=w*16+fr) ----
#pragma unroll
  for (int r = 0; r < 4; ++r) L[kg * 4 + r][w * 16 + fr] = acc[r];
  __syncthreads();

  // ---- per-token finalize: inv_rms, Z, softmaxes ----
  if (t < 16) {
    const int tok = tok0 + t;
    const float inv = rsqrtf(sums[t] * (1.0f / (float)WD) + EPS_RMS);
    float4 zv;
#pragma unroll
    for (int e4 = 0; e4 < 4; ++e4) {
      zv.x = fmaf(L[t][e4 * 4 + 0], inv, baseRes[e4 * 4 + 0]);
      zv.y = fmaf(L[t][e4 * 4 + 1], inv, baseRes[e4 * 4 + 1]);
      zv.z = fmaf(L[t][e4 * 4 + 2], inv, baseRes[e4 * 4 + 2]);
      zv.w = fmaf(L[t][e4 * 4 + 3], inv, baseRes[e4 * 4 + 3]);
      *(float4*)(Zout + (size_t)tok * 16 + e4 * 4) = zv;
    }
    // H_pre softmax -> LDS
    {
      float p[4];
#pragma unroll
      for (int j = 0; j < 4; ++j) p[j] = fmaf(L[t][16 + j], inv, basePre[j]);
      const float m = fmaxf(fmaxf(p[0], p[1]), fmaxf(p[2], p[3]));
      float s = 0.f;
#pragma unroll
      for (int j = 0; j < 4; ++j) { p[j] = __expf(p[j] - m); s += p[j]; }
      const float rs = 1.0f / s;
#pragma unroll
      for (int j = 0; j < 4; ++j) HpreS[t][j] = p[j] * rs;
    }
    // H_post softmax -> global
    {
      float q[4];
#pragma unroll
      for (int j = 0; j < 4; ++j) q[j] = fmaf(L[t][20 + j], inv, basePost[j]);
      const float m = fmaxf(fmaxf(q[0], q[1]), fmaxf(q[2], q[3]));
      float s = 0.f;
#pragma unroll
      for (int j = 0; j < 4; ++j) { q[j] = __expf(q[j] - m); s += q[j]; }
      const float rs = 1.0f / s;
      float4 qv; qv.x = q[0] * rs; qv.y = q[1] * rs; qv.z = q[2] * rs; qv.w = q[3] * rs;
      *(float4*)(HpostOut + (size_t)tok * 4) = qv;
    }
  }
  __syncthreads();

  // ---- phase 2: x_pre = sum_n Hpre[n]*x[:, n*C+c] (f16), 8 quarters x 2 passes ----
  const int q16 = t >> 4;
  const int l16 = t & 15;
#pragma unroll
  for (int pass = 0; pass < 2; ++pass) {
    const int tl = pass * 8 + q16;
    const int tok = tok0 + tl;
    const float p0 = HpreS[tl][0], p1 = HpreS[tl][1], p2 = HpreS[tl][2], p3 = HpreS[tl][3];
    const float* xr = x + (size_t)tok * WD;
    _Float16* xp = xpre + (size_t)tok * CD;
#pragma unroll 2
    for (int it = 0; it < 16; ++it) {
      const int c4 = it * 64 + l16 * 4;
      const float4 s0 = *(const float4*)(xr + c4);
      const float4 s1 = *(const float4*)(xr + CD + c4);
      const float4 s2 = *(const float4*)(xr + 2 * CD + c4);
      const float4 s3 = *(const float4*)(xr + 3 * CD + c4);
      half4v h;
      h[0] = (_Float16)(p0 * s0.x + p1 * s1.x + p2 * s2.x + p3 * s3.x);
      h[1] = (_Float16)(p0 * s0.y + p1 * s1.y + p2 * s2.y + p3 * s3.y);
      h[2] = (_Float16)(p0 * s0.z + p1 * s1.z + p2 * s2.z + p3 * s3.z);
      h[3] = (_Float16)(p0 * s0.w + p1 * s1.w + p2 * s2.w + p3 * s3.w);
      *(half4v*)(xp + c4) = h;
    }
  }
}

// ================= Kernel C: log-domain Sinkhorn (50 iters) + gate =================
__global__ __launch_bounds__(256) void k_sinkhorn(const float* __restrict__ Zin,
                                                  const float* __restrict__ gate,
                                                  float* __restrict__ HresF) {
  const int tid = threadIdx.x;
  const int l16 = tid & 15;
  const int tok = blockIdx.x * 16 + (tid >> 4);
  const float Z = Zin[(size_t)tok * 16 + l16] * TAU_INV;
  const int i = l16 >> 2, j = l16 & 3;
  float u = 0.0f, v = 0.0f;
  for (int itr = 0; itr < 50; ++itr) {
    float a = Z + v;
    float m = fmaxf(a, __shfl_xor(a, 1)); m = fmaxf(m, __shfl_xor(m, 2));
    float s = __expf(a - m);
    s += __shfl_xor(s, 1); s += __shfl_xor(s, 2);
    u = -(m + __logf(s));
    float b = Z + u;
    float m2 = fmaxf(b, __shfl_xor(b, 4)); m2 = fmaxf(m2, __shfl_xor(m2, 8));
    float s2 = __expf(b - m2);
    s2 += __shfl_xor(s2, 4); s2 += __shfl_xor(s2, 8);
    v = -(m2 + __logf(s2));
  }
  const float H = __expf(Z + u + v);
  const float g = 1.0f / (1.0f + __expf(-gate[0]));
  HresF[(size_t)tok * 16 + l16] = g * H + ((i == j) ? (1.0f - g) : 0.0f);
}

// ================= Kernel D: y = x_pre @ W_branch (f16 MFMA) + fused epilogue =====
#define LDK 72
__global__ __launch_bounds__(256, 2) void k_gemm_epi(
    const _Float16* __restrict__ xpre, const _Float16* __restrict__ WT,
    const float* __restrict__ x, const float* __restrict__ HresF,
    const float* __restrict__ Hpost, float* __restrict__ out)
{
  __shared__ _Float16 As[128 * LDK];
  __shared__ _Float16 Bs[128 * LDK];
  const int tid  = threadIdx.x;
  const int nb   = blockIdx.x & 7;
  const int mb   = blockIdx.x >> 3;
  const int tok0 = mb * 128;
  const int cb   = nb * 128;
  const int lane = tid & 63, wid = tid >> 6;
  const int wr = (wid >> 1) * 64, wc = (wid & 1) * 64;
  const int fr = lane & 15, kg = lane >> 4;

  f32x4 acc[4][4];
#pragma unroll
  for (int m = 0; m < 4; ++m)
#pragma unroll
    for (int n = 0; n < 4; ++n) { f32x4 z = {0.f, 0.f, 0.f, 0.f}; acc[m][n] = z; }

  for (int kt = 0; kt < 16; ++kt) {
#pragma unroll
    for (int i = 0; i < 4; ++i) {
      const int chunk = tid + i * 256;
      const int r = chunk >> 3;
      const int ko = (chunk & 7) * 8;
      *(half8*)&As[r * LDK + ko] =
          *(const half8*)&xpre[(size_t)(tok0 + r) * CD + kt * 64 + ko];
      *(half8*)&Bs[r * LDK + ko] =
          *(const half8*)&WT[(size_t)(cb + r) * CD + kt * 64 + ko];
    }
    __syncthreads();
#pragma unroll
    for (int kk = 0; kk < 2; ++kk) {
      half8 a[4], b[4];
#pragma unroll
      for (int m = 0; m < 4; ++m)
        a[m] = *(const half8*)&As[(wr + m * 16 + fr) * LDK + kk * 32 + kg * 8];
#pragma unroll
      for (int n = 0; n < 4; ++n)
        b[n] = *(const half8*)&Bs[(wc + n * 16 + fr) * LDK + kk * 32 + kg * 8];
#pragma unroll
      for (int m = 0; m < 4; ++m)
#pragma unroll
        for (int n = 0; n < 4; ++n)
          acc[m][n] = __builtin_amdgcn_mfma_f32_16x16x32_f16(a[m], b[n], acc[m][n], 0, 0, 0);
    }
    __syncthreads();
  }

  float* Hs = (float*)As;
  for (int idx = tid; idx < 128 * 20; idx += 256) {
    const int tl = idx / 20, e = idx % 20;
    Hs[idx] = (e < 16) ? HresF[(size_t)(tok0 + tl) * 16 + e]
                       : Hpost[(size_t)(tok0 + tl) * 4 + (e - 16)];
  }
  __syncthreads();

#pragma unroll
  for (int m = 0; m < 4; ++m) {
#pragma unroll
    for (int reg = 0; reg < 4; ++reg) {
      const int tl = wr + m * 16 + (lane >> 4) * 4 + reg;
      const size_t trow = (size_t)(tok0 + tl) * WD;
      float H[20];
#pragma unroll
      for (int e = 0; e < 20; ++e) H[e] = Hs[tl * 20 + e];
#pragma unroll
      for (int n = 0; n < 4; ++n) {
        const int c = cb + wc + n * 16 + (lane & 15);
        const float yv = acc[m][n][reg];
        const float x0 = x[trow + c];
        const float x1 = x[trow + CD + c];
        const float x2 = x[trow + 2 * CD + c];
        const float x3 = x[trow + 3 * CD + c];
#pragma unroll
        for (int i = 0; i < 4; ++i) {
          out[trow + i * CD + c] =
              H[i * 4 + 0] * x0 + H[i * 4 + 1] * x1 + H[i * 4 + 2] * x2 +
              H[i * 4 + 3] * x3 + H[16 + i] * yv;
        }
      }
    }
  }
}

// ================= launcher =================
extern "C" void kernel_launch(void* const* d_in, const int* in_sizes, int n_in,
                              void* d_out, int out_size, void* d_ws, size_t ws_size,
                              hipStream_t stream) {
  const float* x        = (const float*)d_in[0];
  const float* Wres     = (const float*)d_in[1];
  const float* Wpre     = (const float*)d_in[2];
  const float* Wpost    = (const float*)d_in[3];
  const float* baseRes  = (const float*)d_in[4];
  const float* basePre  = (const float*)d_in[5];
  const float* basePost = (const float*)d_in[6];
  const float* gate     = (const float*)d_in[7];
  const float* Wb       = (const float*)d_in[8];
  float* out = (float*)d_out;

  char* ws = (char*)d_ws;
  _Float16* xpre  = (_Float16*)(ws);                       // 16,777,216 B
  _Float16* WT    = (_Float16*)(ws + 16777216);            //  2,097,152 B
  float*    Z     = (float*)(ws + 18874368);               //    524,288 B
  float*    HresF = (float*)(ws + 19398656);               //    524,288 B
  float*    Hpst  = (float*)(ws + 19922944);               //    131,072 B
  _Float16* Wcat  = (_Float16*)(ws + 20054016);            //    262,144 B

  k_wt<<<256, 256, 0, stream>>>(Wb, WT);
  k_wcat<<<128, 256, 0, stream>>>(Wres, Wpre, Wpost, Wcat);
  k_stats2<<<512, 128, 0, stream>>>(x, Wcat, baseRes, basePre, basePost,
                                    Z, Hpst, xpre);
  k_sinkhorn<<<512, 256, 0, stream>>>(Z, gate, HresF);
  k_gemm_epi<<<512, 256, 0, stream>>>(xpre, WT, x, HresF, Hpst, out);
}

// Round 3
// 127.974 us; speedup vs baseline: 3.8046x; 1.2576x over previous
//
#include <hip/hip_runtime.h>
#include <cstdint>
#include <cstddef>

// ---------------- problem constants ----------------
#define NTOK 8192            // B*T = 4*2048
#define WD   4096            // n*C
#define CD   1024            // C (per-stream channels)
#define EPS_RMS 1.1920929e-07f
#define TAU_INV 10.0f        // 1/0.1

using half8  = __attribute__((ext_vector_type(8))) _Float16;
using half4v = __attribute__((ext_vector_type(4))) _Float16;
using f32x4  = __attribute__((ext_vector_type(4))) float;

// ================= Kernel A: W_branch fp32 [k][c] -> WT f16 [c][k] =================
__global__ __launch_bounds__(256) void k_wt(const float* __restrict__ W,
                                            _Float16* __restrict__ WT) {
  __shared__ float tile[64][65];
  const int t  = threadIdx.x;
  const int c0 = (blockIdx.x & 15) * 64;
  const int k0 = (blockIdx.x >> 4) * 64;
  const int a = t & 63, b = t >> 6;
#pragma unroll
  for (int i = 0; i < 16; ++i) {
    int k = b + i * 4;
    tile[k][a] = W[(size_t)(k0 + k) * CD + (c0 + a)];
  }
  __syncthreads();
#pragma unroll
  for (int i = 0; i < 16; ++i) {
    int c = b + i * 4;
    WT[(size_t)(c0 + c) * CD + (k0 + a)] = (_Float16)tile[a][c];
  }
}

// ================= Kernel A2: concat projection weights -> Wcat f16 [32][4096] ======
__global__ __launch_bounds__(256) void k_wcat(const float* __restrict__ Wres,
                                              const float* __restrict__ Wpre,
                                              const float* __restrict__ Wpost,
                                              _Float16* __restrict__ Wcat) {
  const int id  = blockIdx.x * 256 + threadIdx.x;
  const int row = id >> 10;
  const int kq  = id & 1023;
  float4 v = make_float4(0.f, 0.f, 0.f, 0.f);
  if (row < 16)      v = *(const float4*)(Wres + (size_t)row * WD + kq * 4);
  else if (row < 20) v = *(const float4*)(Wpre + (size_t)(row - 16) * WD + kq * 4);
  else if (row < 24) v = *(const float4*)(Wpost + (size_t)(row - 20) * WD + kq * 4);
  half4v h;
  h[0] = (_Float16)v.x; h[1] = (_Float16)v.y; h[2] = (_Float16)v.z; h[3] = (_Float16)v.w;
  *(half4v*)(Wcat + (size_t)row * WD + kq * 4) = h;
}

// ================= Kernel B: MFMA stats v3 =================
// 512 thr (8 waves), 16 tokens/block. K split 4 ways across wave-pairs
// (pair p: K in [p*1024, p*1024+1024), 16 steps of BK=64), double-buffered LDS,
// partial logits/sumsq merged via LDS. Tail: waves 0-3 run inlined 50-iter
// Sinkhorn (VALU latency) CONCURRENTLY with waves 4-7 computing x_pre (memory).
#define LDA 72   // padded K-stride in f16 elems
__global__ __launch_bounds__(512, 4) void k_stats3(
    const float* __restrict__ x, const _Float16* __restrict__ Wcat,
    const float* __restrict__ baseRes, const float* __restrict__ basePre,
    const float* __restrict__ basePost, const float* __restrict__ gate,
    float* __restrict__ HpostOut, float* __restrict__ HresF,
    _Float16* __restrict__ xpre)
{
  __shared__ _Float16 As[2][4][16 * LDA];   // 18.4 KB
  __shared__ _Float16 Bs[2][4][32 * LDA];   // 36.9 KB
  __shared__ float Lpart[4][16][32];        //  8.2 KB
  __shared__ float ssPart[4][16];
  __shared__ float invS[16];
  __shared__ float HpreS[16][4];

  const int t    = threadIdx.x;          // 0..511
  const int lane = t & 63;
  const int wid  = t >> 6;
  const int p    = wid >> 1;             // K-chunk 0..3
  const int g    = wid & 1;              // n-group (cols g*16..g*16+15)
  const int tp   = t & 127;              // index within wave pair
  const int tok0 = blockIdx.x * 16;
  const int fr   = lane & 15, kg = lane >> 4;

  // staging ownership within the pair
  const int ar = tp >> 4;                // A rows ar, ar+8
  const int ak = (tp & 15) * 4;
  const int br = tp >> 3;                // B rows br, br+16
  const int bk = (tp & 7) * 8;
  const int Kb = p * 1024;

  f32x4 acc = {0.f, 0.f, 0.f, 0.f};
  float ss0 = 0.f, ss1 = 0.f;

  const float* xa0 = x + (size_t)(tok0 + ar) * WD + Kb + ak;
  const float* xa1 = x + (size_t)(tok0 + ar + 8) * WD + Kb + ak;
  const _Float16* wb0 = Wcat + (size_t)br * WD + Kb + bk;
  const _Float16* wb1 = Wcat + (size_t)(br + 16) * WD + Kb + bk;

  // ---- preload + commit step 0 ----
  float4 a0 = *(const float4*)(xa0);
  float4 a1 = *(const float4*)(xa1);
  half8 b0 = *(const half8*)(wb0);
  half8 b1 = *(const half8*)(wb1);
  {
    ss0 += a0.x * a0.x + a0.y * a0.y + a0.z * a0.z + a0.w * a0.w;
    ss1 += a1.x * a1.x + a1.y * a1.y + a1.z * a1.z + a1.w * a1.w;
    half4v h0, h1;
    h0[0] = (_Float16)a0.x; h0[1] = (_Float16)a0.y; h0[2] = (_Float16)a0.z; h0[3] = (_Float16)a0.w;
    h1[0] = (_Float16)a1.x; h1[1] = (_Float16)a1.y; h1[2] = (_Float16)a1.z; h1[3] = (_Float16)a1.w;
    *(half4v*)&As[0][p][ar * LDA + ak] = h0;
    *(half4v*)&As[0][p][(ar + 8) * LDA + ak] = h1;
    *(half8*)&Bs[0][p][br * LDA + bk] = b0;
    *(half8*)&Bs[0][p][(br + 16) * LDA + bk] = b1;
  }
  __syncthreads();

  int cur = 0;
  for (int kt = 0; kt < 16; ++kt) {
    // prefetch step kt+1 into regs
    if (kt < 15) {
      const int ko = (kt + 1) * 64;
      a0 = *(const float4*)(xa0 + ko);
      a1 = *(const float4*)(xa1 + ko);
      b0 = *(const half8*)(wb0 + ko);
      b1 = *(const half8*)(wb1 + ko);
    }
    // fragments + MFMA from buf[cur]
    half8 af0 = *(const half8*)&As[cur][p][fr * LDA + kg * 8];
    half8 af1 = *(const half8*)&As[cur][p][fr * LDA + 32 + kg * 8];
    half8 bf0 = *(const half8*)&Bs[cur][p][(g * 16 + fr) * LDA + kg * 8];
    half8 bf1 = *(const half8*)&Bs[cur][p][(g * 16 + fr) * LDA + 32 + kg * 8];
    acc = __builtin_amdgcn_mfma_f32_16x16x32_f16(af0, bf0, acc, 0, 0, 0);
    acc = __builtin_amdgcn_mfma_f32_16x16x32_f16(af1, bf1, acc, 0, 0, 0);
    // commit kt+1 into buf[cur^1]
    if (kt < 15) {
      ss0 += a0.x * a0.x + a0.y * a0.y + a0.z * a0.z + a0.w * a0.w;
      ss1 += a1.x * a1.x + a1.y * a1.y + a1.z * a1.z + a1.w * a1.w;
      half4v h0, h1;
      h0[0] = (_Float16)a0.x; h0[1] = (_Float16)a0.y; h0[2] = (_Float16)a0.z; h0[3] = (_Float16)a0.w;
      h1[0] = (_Float16)a1.x; h1[1] = (_Float16)a1.y; h1[2] = (_Float16)a1.z; h1[3] = (_Float16)a1.w;
      *(half4v*)&As[cur ^ 1][p][ar * LDA + ak] = h0;
      *(half4v*)&As[cur ^ 1][p][(ar + 8) * LDA + ak] = h1;
      *(half8*)&Bs[cur ^ 1][p][br * LDA + bk] = b0;
      *(half8*)&Bs[cur ^ 1][p][(br + 16) * LDA + bk] = b1;
    }
    __syncthreads();
    cur ^= 1;
  }

  // ---- partial sumsq: butterfly within 16-thread groups (aligned in-wave) ----
#define QR(v) { v += __shfl_xor(v, 1); v += __shfl_xor(v, 2); \
                v += __shfl_xor(v, 4); v += __shfl_xor(v, 8); }
  QR(ss0) QR(ss1)
#undef QR
  if ((tp & 15) == 0) { ssPart[p][ar] = ss0; ssPart[p][ar + 8] = ss1; }

  // ---- partial logits scatter (C/D map: row=kg*4+r, col=g*16+fr) ----
#pragma unroll
  for (int r = 0; r < 4; ++r) Lpart[p][kg * 4 + r][g * 16 + fr] = acc[r];
  __syncthreads();

  // ---- per-token finalize ----
  if (t < 16) {
    const float s = ssPart[0][t] + ssPart[1][t] + ssPart[2][t] + ssPart[3][t];
    const float inv = rsqrtf(s * (1.0f / (float)WD) + EPS_RMS);
    invS[t] = inv;
    float pr[4], q[4];
#pragma unroll
    for (int j = 0; j < 4; ++j) {
      const float lp = Lpart[0][t][16 + j] + Lpart[1][t][16 + j] +
                       Lpart[2][t][16 + j] + Lpart[3][t][16 + j];
      pr[j] = fmaf(lp, inv, basePre[j]);
      const float lq = Lpart[0][t][20 + j] + Lpart[1][t][20 + j] +
                       Lpart[2][t][20 + j] + Lpart[3][t][20 + j];
      q[j] = fmaf(lq, inv, basePost[j]);
    }
    {
      const float m = fmaxf(fmaxf(pr[0], pr[1]), fmaxf(pr[2], pr[3]));
      float s2 = 0.f;
#pragma unroll
      for (int j = 0; j < 4; ++j) { pr[j] = __expf(pr[j] - m); s2 += pr[j]; }
      const float rs = 1.0f / s2;
#pragma unroll
      for (int j = 0; j < 4; ++j) HpreS[t][j] = pr[j] * rs;
    }
    {
      const float m = fmaxf(fmaxf(q[0], q[1]), fmaxf(q[2], q[3]));
      float s2 = 0.f;
#pragma unroll
      for (int j = 0; j < 4; ++j) { q[j] = __expf(q[j] - m); s2 += q[j]; }
      const float rs = 1.0f / s2;
      float4 qv; qv.x = q[0] * rs; qv.y = q[1] * rs; qv.z = q[2] * rs; qv.w = q[3] * rs;
      *(float4*)(HpostOut + (size_t)(tok0 + t) * 4) = qv;
    }
  }
  __syncthreads();

  if (t < 256) {
    // ---- inlined Sinkhorn: waves 0-3, 16 lanes per token ----
    const int tk  = t >> 4;
    const int l16 = t & 15;
    const float Lsum = Lpart[0][tk][l16] + Lpart[1][tk][l16] +
                       Lpart[2][tk][l16] + Lpart[3][tk][l16];
    const float Z = fmaf(Lsum, invS[tk], baseRes[l16]) * TAU_INV;
    const int i = l16 >> 2, j = l16 & 3;
    float u = 0.0f, v = 0.0f;
    for (int itr = 0; itr < 50; ++itr) {
      float a = Z + v;
      float m = fmaxf(a, __shfl_xor(a, 1)); m = fmaxf(m, __shfl_xor(m, 2));
      float s = __expf(a - m);
      s += __shfl_xor(s, 1); s += __shfl_xor(s, 2);
      u = -(m + __logf(s));
      float b = Z + u;
      float m2 = fmaxf(b, __shfl_xor(b, 4)); m2 = fmaxf(m2, __shfl_xor(m2, 8));
      float s2 = __expf(b - m2);
      s2 += __shfl_xor(s2, 4); s2 += __shfl_xor(s2, 8);
      v = -(m2 + __logf(s2));
    }
    const float H = __expf(Z + u + v);
    const float gg = 1.0f / (1.0f + __expf(-gate[0]));
    HresF[(size_t)(tok0 + tk) * 16 + l16] = gg * H + ((i == j) ? (1.0f - gg) : 0.0f);
  } else {
    // ---- phase 2: waves 4-7, one 16-lane quarter per token ----
    const int q16 = (t - 256) >> 4;       // token 0..15
    const int l16 = t & 15;
    const int tok = tok0 + q16;
    const float p0 = HpreS[q16][0], p1 = HpreS[q16][1];
    const float p2 = HpreS[q16][2], p3 = HpreS[q16][3];
    const float* xr = x + (size_t)tok * WD;
    _Float16* xp = xpre + (size_t)tok * CD;
#pragma unroll 2
    for (int it = 0; it < 16; ++it) {
      const int c4 = it * 64 + l16 * 4;
      const float4 s0 = *(const float4*)(xr + c4);
      const float4 s1 = *(const float4*)(xr + CD + c4);
      const float4 s2 = *(const float4*)(xr + 2 * CD + c4);
      const float4 s3 = *(const float4*)(xr + 3 * CD + c4);
      half4v h;
      h[0] = (_Float16)(p0 * s0.x + p1 * s1.x + p2 * s2.x + p3 * s3.x);
      h[1] = (_Float16)(p0 * s0.y + p1 * s1.y + p2 * s2.y + p3 * s3.y);
      h[2] = (_Float16)(p0 * s0.z + p1 * s1.z + p2 * s2.z + p3 * s3.z);
      h[3] = (_Float16)(p0 * s0.w + p1 * s1.w + p2 * s2.w + p3 * s3.w);
      *(half4v*)(xp + c4) = h;
    }
  }
}

// ================= Kernel D: y = x_pre @ W_branch (f16 MFMA) + fused epilogue =====
#define LDK 72
__global__ __launch_bounds__(256, 2) void k_gemm_epi(
    const _Float16* __restrict__ xpre, const _Float16* __restrict__ WT,
    const float* __restrict__ x, const float* __restrict__ HresF,
    const float* __restrict__ Hpost, float* __restrict__ out)
{
  __shared__ _Float16 As[128 * LDK];
  __shared__ _Float16 Bs[128 * LDK];
  const int tid  = threadIdx.x;
  const int nb   = blockIdx.x & 7;
  const int mb   = blockIdx.x >> 3;
  const int tok0 = mb * 128;
  const int cb   = nb * 128;
  const int lane = tid & 63, wid = tid >> 6;
  const int wr = (wid >> 1) * 64, wc = (wid & 1) * 64;
  const int fr = lane & 15, kg = lane >> 4;

  f32x4 acc[4][4];
#pragma unroll
  for (int m = 0; m < 4; ++m)
#pragma unroll
    for (int n = 0; n < 4; ++n) { f32x4 z = {0.f, 0.f, 0.f, 0.f}; acc[m][n] = z; }

  for (int kt = 0; kt < 16; ++kt) {
#pragma unroll
    for (int i = 0; i < 4; ++i) {
      const int chunk = tid + i * 256;
      const int r = chunk >> 3;
      const int ko = (chunk & 7) * 8;
      *(half8*)&As[r * LDK + ko] =
          *(const half8*)&xpre[(size_t)(tok0 + r) * CD + kt * 64 + ko];
      *(half8*)&Bs[r * LDK + ko] =
          *(const half8*)&WT[(size_t)(cb + r) * CD + kt * 64 + ko];
    }
    __syncthreads();
#pragma unroll
    for (int kk = 0; kk < 2; ++kk) {
      half8 a[4], b[4];
#pragma unroll
      for (int m = 0; m < 4; ++m)
        a[m] = *(const half8*)&As[(wr + m * 16 + fr) * LDK + kk * 32 + kg * 8];
#pragma unroll
      for (int n = 0; n < 4; ++n)
        b[n] = *(const half8*)&Bs[(wc + n * 16 + fr) * LDK + kk * 32 + kg * 8];
#pragma unroll
      for (int m = 0; m < 4; ++m)
#pragma unroll
        for (int n = 0; n < 4; ++n)
          acc[m][n] = __builtin_amdgcn_mfma_f32_16x16x32_f16(a[m], b[n], acc[m][n], 0, 0, 0);
    }
    __syncthreads();
  }

  float* Hs = (float*)As;
  for (int idx = tid; idx < 128 * 20; idx += 256) {
    const int tl = idx / 20, e = idx % 20;
    Hs[idx] = (e < 16) ? HresF[(size_t)(tok0 + tl) * 16 + e]
                       : Hpost[(size_t)(tok0 + tl) * 4 + (e - 16)];
  }
  __syncthreads();

#pragma unroll
  for (int m = 0; m < 4; ++m) {
#pragma unroll
    for (int reg = 0; reg < 4; ++reg) {
      const int tl = wr + m * 16 + (lane >> 4) * 4 + reg;
      const size_t trow = (size_t)(tok0 + tl) * WD;
      float H[20];
#pragma unroll
      for (int e = 0; e < 20; ++e) H[e] = Hs[tl * 20 + e];
#pragma unroll
      for (int n = 0; n < 4; ++n) {
        const int c = cb + wc + n * 16 + (lane & 15);
        const float yv = acc[m][n][reg];
        const float x0 = x[trow + c];
        const float x1 = x[trow + CD + c];
        const float x2 = x[trow + 2 * CD + c];
        const float x3 = x[trow + 3 * CD + c];
#pragma unroll
        for (int i = 0; i < 4; ++i) {
          out[trow + i * CD + c] =
              H[i * 4 + 0] * x0 + H[i * 4 + 1] * x1 + H[i * 4 + 2] * x2 +
              H[i * 4 + 3] * x3 + H[16 + i] * yv;
        }
      }
    }
  }
}

// ================= launcher =================
extern "C" void kernel_launch(void* const* d_in, const int* in_sizes, int n_in,
                              void* d_out, int out_size, void* d_ws, size_t ws_size,
                              hipStream_t stream) {
  const float* x        = (const float*)d_in[0];
  const float* Wres     = (const float*)d_in[1];
  const float* Wpre     = (const float*)d_in[2];
  const float* Wpost    = (const float*)d_in[3];
  const float* baseRes  = (const float*)d_in[4];
  const float* basePre  = (const float*)d_in[5];
  const float* basePost = (const float*)d_in[6];
  const float* gate     = (const float*)d_in[7];
  const float* Wb       = (const float*)d_in[8];
  float* out = (float*)d_out;

  char* ws = (char*)d_ws;
  _Float16* xpre  = (_Float16*)(ws);                       // 16,777,216 B
  _Float16* WT    = (_Float16*)(ws + 16777216);            //  2,097,152 B
  float*    HresF = (float*)(ws + 19398656);               //    524,288 B
  float*    Hpst  = (float*)(ws + 19922944);               //    131,072 B
  _Float16* Wcat  = (_Float16*)(ws + 20054016);            //    262,144 B

  k_wt<<<256, 256, 0, stream>>>(Wb, WT);
  k_wcat<<<128, 256, 0, stream>>>(Wres, Wpre, Wpost, Wcat);
  k_stats3<<<512, 512, 0, stream>>>(x, Wcat, baseRes, basePre, basePost, gate,
                                    Hpst, HresF, xpre);
  k_gemm_epi<<<512, 256, 0, stream>>>(xpre, WT, x, HresF, Hpst, out);
}